// Round 1
// baseline (1515.398 us; speedup 1.0000x reference)
//
#include <hip/hip_runtime.h>
#include <hip/hip_bf16.h>
#include <math.h>

#define BN_EPS 1e-5f
#define RES_SCALE 0.7f
#define HIDC 64  // hidden dim, hard-coded (in_sizes[3] == 64)

// ---------------- init ----------------
__global__ __launch_bounds__(256) void k_zero(int* counts, int* cursor, float* stats, int N, int S) {
    int i = blockIdx.x * 256 + threadIdx.x;
    if (i < N) { counts[i] = 0; cursor[i] = 0; }
    if (i < S) stats[i] = 0.0f;
}

// ---------------- degree / CSR build ----------------
__global__ __launch_bounds__(256) void k_count(const int* __restrict__ edges, int E, int* __restrict__ counts) {
    int e = blockIdx.x * 256 + threadIdx.x;
    if (e < E) atomicAdd(&counts[edges[E + e]], 1);   // dst = edges[1][e]
}

__global__ __launch_bounds__(256) void k_dinv(const int* __restrict__ counts, float* __restrict__ dinv, int N) {
    int i = blockIdx.x * 256 + threadIdx.x;
    if (i < N) dinv[i] = rsqrtf((float)counts[i] + 1.0f);  // deg = in-degree + self-loop
}

// exclusive scan of counts -> rowstart, 3-kernel (chunk = 1024 per block)
__global__ __launch_bounds__(256) void k_scan1(const int* __restrict__ counts, int* __restrict__ bsum, int N) {
    __shared__ int sd[256];
    int t = threadIdx.x;
    int base = blockIdx.x * 1024 + t * 4;
    int s = 0;
    if (base + 3 < N) { int4 v = *(const int4*)(counts + base); s = v.x + v.y + v.z + v.w; }
    else { for (int j = 0; j < 4; ++j) if (base + j < N) s += counts[base + j]; }
    sd[t] = s; __syncthreads();
    for (int off = 128; off > 0; off >>= 1) { if (t < off) sd[t] += sd[t + off]; __syncthreads(); }
    if (t == 0) bsum[blockIdx.x] = sd[0];
}

__global__ void k_scan2(int* bsum, int B, int* rowstart, int N) {
    if (threadIdx.x == 0 && blockIdx.x == 0) {
        int run = 0;
        for (int b = 0; b < B; ++b) { int v = bsum[b]; bsum[b] = run; run += v; }
        rowstart[N] = run;
    }
}

__global__ __launch_bounds__(256) void k_scan3(const int* __restrict__ counts, const int* __restrict__ bsum,
                                               int* __restrict__ rowstart, int N) {
    __shared__ int sd[256];
    int t = threadIdx.x;
    int base = blockIdx.x * 1024 + t * 4;
    int v0 = 0, v1 = 0, v2 = 0, v3 = 0;
    if (base + 3 < N) { int4 v = *(const int4*)(counts + base); v0 = v.x; v1 = v.y; v2 = v.z; v3 = v.w; }
    else {
        if (base < N) v0 = counts[base];
        if (base + 1 < N) v1 = counts[base + 1];
        if (base + 2 < N) v2 = counts[base + 2];
        if (base + 3 < N) v3 = counts[base + 3];
    }
    int s = v0 + v1 + v2 + v3;
    sd[t] = s; __syncthreads();
    for (int off = 1; off < 256; off <<= 1) {
        int add = (t >= off) ? sd[t - off] : 0;
        __syncthreads();
        sd[t] += add;
        __syncthreads();
    }
    int excl = sd[t] - s + bsum[blockIdx.x];
    if (base < N)     rowstart[base]     = excl;
    if (base + 1 < N) rowstart[base + 1] = excl + v0;
    if (base + 2 < N) rowstart[base + 2] = excl + v0 + v1;
    if (base + 3 < N) rowstart[base + 3] = excl + v0 + v1 + v2;
}

__global__ __launch_bounds__(256) void k_scatter(const int* __restrict__ edges, int E,
                                                 const int* __restrict__ rowstart, int* __restrict__ cursor,
                                                 const float* __restrict__ dinv,
                                                 int* __restrict__ colA, float* __restrict__ ewA) {
    int e = blockIdx.x * 256 + threadIdx.x;
    if (e >= E) return;
    int s = edges[e], d = edges[E + e];
    int pos = rowstart[d] + atomicAdd(&cursor[d], 1);
    colA[pos] = s;
    ewA[pos] = dinv[s] * dinv[d];
}

// ---------------- tiled fp32 matmul: C[N,64] = X[N,K] @ W[K,64] ----------------
__global__ __launch_bounds__(256) void k_matmul(const float* __restrict__ X, const float* __restrict__ W,
                                                float* __restrict__ C, int N, int K) {
    __shared__ float Xs[64][68];  // [row][k], pad 68 (16B-aligned rows, conflict-friendly)
    __shared__ float Ws[64][64];  // [k][col]
    int t = threadIdx.x;
    int row0 = blockIdx.x * 64;
    int tx = t & 15, ty = t >> 4;  // tx: col/4, ty: row/4
    float acc[4][4] = {};
    for (int kt = 0; kt < K; kt += 64) {
        #pragma unroll
        for (int i = 0; i < 4; ++i) {
            int idx = t + i * 256;
            int row = idx >> 4, c4 = idx & 15;
            int gr = row0 + row, gk = kt + c4 * 4;
            float4 v = make_float4(0.f, 0.f, 0.f, 0.f);
            if (gr < N && gk < K) v = *(const float4*)(X + (size_t)gr * K + gk);
            *(float4*)&Xs[row][c4 * 4] = v;
        }
        #pragma unroll
        for (int i = 0; i < 4; ++i) {
            int idx = t + i * 256;
            int kk = idx >> 4, c4 = idx & 15;
            int gk = kt + kk;
            float4 v = make_float4(0.f, 0.f, 0.f, 0.f);
            if (gk < K) v = *(const float4*)(W + (size_t)gk * HIDC + c4 * 4);
            *(float4*)&Ws[kk][c4 * 4] = v;
        }
        __syncthreads();
        #pragma unroll
        for (int k = 0; k < 64; k += 4) {
            float4 A[4], B[4];
            #pragma unroll
            for (int i = 0; i < 4; ++i) A[i] = *(const float4*)&Xs[ty * 4 + i][k];
            #pragma unroll
            for (int j = 0; j < 4; ++j) B[j] = *(const float4*)&Ws[k + j][tx * 4];
            #pragma unroll
            for (int i = 0; i < 4; ++i) {
                const float* Ai = (const float*)&A[i];
                #pragma unroll
                for (int kk = 0; kk < 4; ++kk) {
                    float a = Ai[kk];
                    const float* Bk = (const float*)&B[kk];
                    acc[i][0] += a * Bk[0];
                    acc[i][1] += a * Bk[1];
                    acc[i][2] += a * Bk[2];
                    acc[i][3] += a * Bk[3];
                }
            }
        }
        __syncthreads();
    }
    #pragma unroll
    for (int i = 0; i < 4; ++i) {
        int gr = row0 + ty * 4 + i;
        if (gr < N)
            *(float4*)(C + (size_t)gr * HIDC + tx * 4) =
                make_float4(acc[i][0], acc[i][1], acc[i][2], acc[i][3]);
    }
}

// ---------------- CSR aggregation: one wave per dst row, lane = feature ----------------
__global__ __launch_bounds__(256) void k_gather(const float* __restrict__ xw, const int* __restrict__ colA,
                                                const float* __restrict__ ewA, const int* __restrict__ rowstart,
                                                const float* __restrict__ dinv, float* __restrict__ agg, int N) {
    int wave = (blockIdx.x * 256 + threadIdx.x) >> 6;
    int lane = threadIdx.x & 63;
    if (wave >= N) return;
    int r = wave;
    float di = dinv[r];
    float acc = xw[(size_t)r * HIDC + lane] * di * di;  // self-loop term
    int b = rowstart[r], e = rowstart[r + 1];
    int i = b;
    for (; i + 1 < e; i += 2) {
        int s0 = colA[i], s1 = colA[i + 1];
        float w0 = ewA[i], w1 = ewA[i + 1];
        float x0 = xw[(size_t)s0 * HIDC + lane];
        float x1 = xw[(size_t)s1 * HIDC + lane];
        acc += x0 * w0 + x1 * w1;
    }
    if (i < e) acc += xw[(size_t)colA[i] * HIDC + lane] * ewA[i];
    agg[(size_t)r * HIDC + lane] = acc;
}

// ---------------- BN stats (sum, sumsq per column) ----------------
__global__ __launch_bounds__(256) void k_stats(const float* __restrict__ x, float* __restrict__ stats, int N) {
    int col = threadIdx.x & 63;
    int sub = threadIdx.x >> 6;  // 0..3
    float s = 0.f, s2 = 0.f;
    for (int r = blockIdx.x * 4 + sub; r < N; r += gridDim.x * 4) {
        float v = x[(size_t)r * HIDC + col];
        s += v; s2 += v * v;
    }
    __shared__ float sd[2][4][64];
    sd[0][sub][col] = s; sd[1][sub][col] = s2;
    __syncthreads();
    if (sub == 0) {
        s  = sd[0][0][col] + sd[0][1][col] + sd[0][2][col] + sd[0][3][col];
        s2 = sd[1][0][col] + sd[1][1][col] + sd[1][2][col] + sd[1][3][col];
        atomicAdd(&stats[col], s);
        atomicAdd(&stats[64 + col], s2);
    }
}

// ---------------- BN apply + ReLU + residual + weighted emb accumulate ----------------
__global__ __launch_bounds__(256) void k_elem(const float* __restrict__ agg, const float* __restrict__ stats,
                                              const float* __restrict__ gamma, const float* __restrict__ beta,
                                              const float* __restrict__ lw, const float* __restrict__ xprev,
                                              float* __restrict__ xcur, float* __restrict__ emb,
                                              int N, int layer, int L) {
    int i = blockIdx.x * 256 + threadIdx.x;
    if (i >= N * HIDC) return;
    int c = i & 63;
    float rN = 1.0f / (float)N;
    float m = stats[c] * rN;
    float var = stats[64 + c] * rN - m * m;
    float inv = rsqrtf(var + BN_EPS);
    float v = (agg[i] - m) * inv * gamma[c] + beta[c];
    v = fmaxf(v, 0.0f);
    if (layer > 0) v += RES_SCALE * xprev[i];
    xcur[i] = v;
    // softmax(lw)[layer]
    float mx = lw[0];
    for (int j = 1; j < L; ++j) mx = fmaxf(mx, lw[j]);
    float sum = 0.f, wl = 0.f;
    for (int j = 0; j < L; ++j) {
        float e = __expf(lw[j] - mx);
        sum += e;
        if (j == layer) wl = e;
    }
    wl /= sum;
    float prev = (layer == 0) ? 0.0f : emb[i];
    emb[i] = prev + wl * v;
}

extern "C" void kernel_launch(void* const* d_in, const int* in_sizes, int n_in,
                              void* d_out, int out_size, void* d_ws, size_t ws_size,
                              hipStream_t stream) {
    const float* features = (const float*)d_in[0];
    const int*   edges    = (const int*)d_in[1];
    const float* W0       = (const float*)d_in[2];
    // d_in[3] = b0: provably cancels through BatchNorm -> skipped (exact)
    const float* Wh       = (const float*)d_in[4];
    // d_in[5] = bh: same
    const float* gamma    = (const float*)d_in[6];
    const float* beta     = (const float*)d_in[7];
    const float* lw       = (const float*)d_in[8];

    const int HID    = in_sizes[3];            // 64
    const int IN_DIM = in_sizes[2] / HID;      // 2000
    const int N      = in_sizes[0] / IN_DIM;   // 50000
    const int E      = in_sizes[1] / 2;        // 1600000
    const int L      = in_sizes[8];            // 4
    float* out = (float*)d_out;

    // workspace carve-out (256B aligned)
    char* ws = (char*)d_ws;
    auto alloc = [&](size_t bytes) { char* p = ws; ws += (bytes + 255) & ~(size_t)255; return p; };
    int*   counts   = (int*)alloc((size_t)N * 4);
    int*   cursor   = (int*)alloc((size_t)N * 4);
    int*   rowstart = (int*)alloc((size_t)(N + 1) * 4);
    int*   bsum     = (int*)alloc(256 * 4);
    float* dinv     = (float*)alloc((size_t)N * 4);
    float* stats    = (float*)alloc((size_t)L * 128 * 4);
    int*   colA     = (int*)alloc((size_t)E * 4);
    float* ewA      = (float*)alloc((size_t)E * 4);
    float* xw       = (float*)alloc((size_t)N * HID * 4);
    float* agg      = (float*)alloc((size_t)N * HID * 4);
    float* x0       = (float*)alloc((size_t)N * HID * 4);
    float* x1       = (float*)alloc((size_t)N * HID * 4);

    int S = L * 128;
    int zgrid = (max(N, S) + 255) / 256;
    k_zero<<<zgrid, 256, 0, stream>>>(counts, cursor, stats, N, S);

    int egrid = (E + 255) / 256;
    int ngrid = (N + 255) / 256;
    k_count<<<egrid, 256, 0, stream>>>(edges, E, counts);
    k_dinv<<<ngrid, 256, 0, stream>>>(counts, dinv, N);

    int B = (N + 1023) / 1024;
    k_scan1<<<B, 256, 0, stream>>>(counts, bsum, N);
    k_scan2<<<1, 64, 0, stream>>>(bsum, B, rowstart, N);
    k_scan3<<<B, 256, 0, stream>>>(counts, bsum, rowstart, N);
    k_scatter<<<egrid, 256, 0, stream>>>(edges, E, rowstart, cursor, dinv, colA, ewA);

    int mmgrid = (N + 63) / 64;
    int ggrid  = (N + 3) / 4;
    int elgrid = ((size_t)N * HID + 255) / 256;

    const float* xc_prev = nullptr;
    for (int l = 0; l < L; ++l) {
        const float* Xin = (l == 0) ? features : xc_prev;
        int K = (l == 0) ? IN_DIM : HID;
        const float* Wl = (l == 0) ? W0 : Wh + (size_t)(l - 1) * HID * HID;
        k_matmul<<<mmgrid, 256, 0, stream>>>(Xin, Wl, xw, N, K);
        k_gather<<<ggrid, 256, 0, stream>>>(xw, colA, ewA, rowstart, dinv, agg, N);
        k_stats<<<256, 256, 0, stream>>>(agg, stats + l * 128, N);
        float* xcur = (l % 2 == 0) ? x0 : x1;
        const float* xprev = (l == 0) ? nullptr : ((l % 2 == 0) ? x1 : x0);
        k_elem<<<elgrid, 256, 0, stream>>>(agg, stats + l * 128, gamma + l * HID, beta + l * HID,
                                           lw, xprev, xcur, out, N, l, L);
        xc_prev = xcur;
    }
}

// Round 2
// 1134.646 us; speedup vs baseline: 1.3356x; 1.3356x over previous
//
#include <hip/hip_runtime.h>
#include <hip/hip_bf16.h>
#include <math.h>

#define BN_EPS 1e-5f
#define RES_SCALE 0.7f

typedef float f4 __attribute__((ext_vector_type(4)));
typedef short s8 __attribute__((ext_vector_type(8)));

__device__ inline short f2bf(float f) {
    __hip_bfloat16 h = __float2bfloat16(f);
    return *reinterpret_cast<short*>(&h);
}

// ---------------- init ----------------
__global__ __launch_bounds__(256) void k_zero(int* counts, int* cursor, float* stats, int N, int S) {
    int i = blockIdx.x * 256 + threadIdx.x;
    if (i < N) { counts[i] = 0; cursor[i] = 0; }
    if (i < S) stats[i] = 0.0f;
}

// ---------------- degree / CSR build ----------------
__global__ __launch_bounds__(256) void k_count(const int* __restrict__ edges, int E, int* __restrict__ counts) {
    int e = blockIdx.x * 256 + threadIdx.x;
    if (e < E) atomicAdd(&counts[edges[E + e]], 1);   // dst = edges[1][e]
}

__global__ __launch_bounds__(256) void k_dinv(const int* __restrict__ counts, float* __restrict__ dinv, int N) {
    int i = blockIdx.x * 256 + threadIdx.x;
    if (i < N) dinv[i] = rsqrtf((float)counts[i] + 1.0f);  // deg = in-degree + self-loop
}

// exclusive scan of counts -> rowstart (chunk = 1024 per block)
__global__ __launch_bounds__(256) void k_scan1(const int* __restrict__ counts, int* __restrict__ bsum, int N) {
    __shared__ int sd[256];
    int t = threadIdx.x;
    int base = blockIdx.x * 1024 + t * 4;
    int s = 0;
    if (base + 3 < N) { int4 v = *(const int4*)(counts + base); s = v.x + v.y + v.z + v.w; }
    else { for (int j = 0; j < 4; ++j) if (base + j < N) s += counts[base + j]; }
    sd[t] = s; __syncthreads();
    for (int off = 128; off > 0; off >>= 1) { if (t < off) sd[t] += sd[t + off]; __syncthreads(); }
    if (t == 0) bsum[blockIdx.x] = sd[0];
}

__global__ void k_scan2(int* bsum, int B, int* rowstart, int N) {
    if (threadIdx.x == 0 && blockIdx.x == 0) {
        int run = 0;
        for (int b = 0; b < B; ++b) { int v = bsum[b]; bsum[b] = run; run += v; }
        rowstart[N] = run;
    }
}

__global__ __launch_bounds__(256) void k_scan3(const int* __restrict__ counts, const int* __restrict__ bsum,
                                               int* __restrict__ rowstart, int N) {
    __shared__ int sd[256];
    int t = threadIdx.x;
    int base = blockIdx.x * 1024 + t * 4;
    int v0 = 0, v1 = 0, v2 = 0, v3 = 0;
    if (base + 3 < N) { int4 v = *(const int4*)(counts + base); v0 = v.x; v1 = v.y; v2 = v.z; v3 = v.w; }
    else {
        if (base < N) v0 = counts[base];
        if (base + 1 < N) v1 = counts[base + 1];
        if (base + 2 < N) v2 = counts[base + 2];
        if (base + 3 < N) v3 = counts[base + 3];
    }
    int s = v0 + v1 + v2 + v3;
    sd[t] = s; __syncthreads();
    for (int off = 1; off < 256; off <<= 1) {
        int add = (t >= off) ? sd[t - off] : 0;
        __syncthreads();
        sd[t] += add;
        __syncthreads();
    }
    int excl = sd[t] - s + bsum[blockIdx.x];
    if (base < N)     rowstart[base]     = excl;
    if (base + 1 < N) rowstart[base + 1] = excl + v0;
    if (base + 2 < N) rowstart[base + 2] = excl + v0 + v1;
    if (base + 3 < N) rowstart[base + 3] = excl + v0 + v1 + v2;
}

__global__ __launch_bounds__(256) void k_scatter(const int* __restrict__ edges, int E,
                                                 const int* __restrict__ rowstart, int* __restrict__ cursor,
                                                 const float* __restrict__ dinv,
                                                 int* __restrict__ colA, float* __restrict__ ewA) {
    int e = blockIdx.x * 256 + threadIdx.x;
    if (e >= E) return;
    int s = edges[e], d = edges[E + e];
    int pos = rowstart[d] + atomicAdd(&cursor[d], 1);
    colA[pos] = s;
    ewA[pos] = dinv[s] * dinv[d];
}

// ---------------- W pre-transpose + bf16 convert: WT[n][k] = bf16(W[k][n]) ----------------
__global__ __launch_bounds__(256) void k_wt(const float* __restrict__ W0, const float* __restrict__ Wh,
                                            short* __restrict__ WT0, short* __restrict__ WTh, int K0) {
    __shared__ short Ts[64][72];
    int b = blockIdx.x, t = threadIdx.x;
    int nk0 = (K0 + 63) >> 6;
    const float* W; short* dst; int K, kt;
    if (b < nk0) { W = W0; dst = WT0; K = K0; kt = b * 64; }
    else { int l = b - nk0; W = Wh + (size_t)l * 64 * 64; dst = WTh + (size_t)l * 64 * 64; K = 64; kt = 0; }
    #pragma unroll
    for (int i = 0; i < 16; ++i) {
        int idx = t + i * 256;
        int r = idx >> 6, c = idx & 63;
        int gk = kt + r;
        Ts[c][r] = (gk < K) ? f2bf(W[(size_t)gk * 64 + c]) : (short)0;
    }
    __syncthreads();
    #pragma unroll
    for (int i = 0; i < 16; ++i) {
        int idx = t + i * 256;
        int n = idx >> 6, r = idx & 63;
        int gk = kt + r;
        if (gk < K) dst[(size_t)n * K + gk] = Ts[n][r];
    }
}

// ---------------- MFMA matmul: Cb[N,64] (bf16) = X[N,K] (fp32) @ WT^T (bf16) ----------------
// block = 256 thr (4 waves), tile 64 rows x 64 cols; wave w: rows w*16..w*16+15.
// k-tile 32, one mfma_f32_16x16x32_bf16 per (row-tile, col-tile) per k-tile.
__global__ __launch_bounds__(256) void k_mm(const float* __restrict__ X, const short* __restrict__ WT,
                                            __hip_bfloat16* __restrict__ Cb, int N, int K) {
    __shared__ float Xs[64][36];   // pad 36: row stride 144B (16B-aligned, 2-way conflicts only)
    __shared__ short Ws[64][40];   // pad 40: row stride 80B
    int t = threadIdx.x;
    int w = t >> 6, lane = t & 63;
    int m = lane & 15, kq = lane >> 4;
    int row0 = blockIdx.x * 64;

    int xr = t >> 3, xc = t & 7;   // X staging: rows xr, xr+32; k-chunk xc (float4)
    int wn = t >> 2, wc = t & 3;   // W staging: row wn, k-chunk wc (8 bf16 = int4)

    f4 acc[4] = {};
    f4 px0, px1; int4 pw;

    // prefetch k-tile 0
    {
        int gr0 = row0 + xr, gr1 = row0 + xr + 32, gk = xc * 4;
        px0 = (gr0 < N && gk < K) ? *(const f4*)(X + (size_t)gr0 * K + gk) : (f4){};
        px1 = (gr1 < N && gk < K) ? *(const f4*)(X + (size_t)gr1 * K + gk) : (f4){};
        int gkw = wc * 8;
        pw = (gkw < K) ? *(const int4*)(WT + (size_t)wn * K + gkw) : make_int4(0, 0, 0, 0);
    }

    for (int kt = 0; kt < K; kt += 32) {
        *(f4*)&Xs[xr][xc * 4] = px0;
        *(f4*)&Xs[xr + 32][xc * 4] = px1;
        *(int4*)&Ws[wn][wc * 8] = pw;
        __syncthreads();

        int kn = kt + 32;
        if (kn < K) {
            int gr0 = row0 + xr, gr1 = row0 + xr + 32, gk = kn + xc * 4;
            px0 = (gr0 < N && gk < K) ? *(const f4*)(X + (size_t)gr0 * K + gk) : (f4){};
            px1 = (gr1 < N && gk < K) ? *(const f4*)(X + (size_t)gr1 * K + gk) : (f4){};
            int gkw = kn + wc * 8;
            pw = (gkw < K) ? *(const int4*)(WT + (size_t)wn * K + gkw) : make_int4(0, 0, 0, 0);
        }

        f4 a0 = *(const f4*)&Xs[w * 16 + m][kq * 8];
        f4 a1 = *(const f4*)&Xs[w * 16 + m][kq * 8 + 4];
        s8 av;
        #pragma unroll
        for (int j = 0; j < 4; ++j) { av[j] = f2bf(a0[j]); av[j + 4] = f2bf(a1[j]); }
        #pragma unroll
        for (int ct = 0; ct < 4; ++ct) {
            s8 bv = *(const s8*)&Ws[ct * 16 + m][kq * 8];
            acc[ct] = __builtin_amdgcn_mfma_f32_16x16x32_bf16(av, bv, acc[ct], 0, 0, 0);
        }
        __syncthreads();
    }

    // C/D layout: col = lane&15, row = (lane>>4)*4 + reg  [measured m89/m91]
    #pragma unroll
    for (int ct = 0; ct < 4; ++ct) {
        #pragma unroll
        for (int reg = 0; reg < 4; ++reg) {
            int gr = row0 + w * 16 + kq * 4 + reg;
            if (gr < N) Cb[(size_t)gr * 64 + ct * 16 + m] = __float2bfloat16(acc[ct][reg]);
        }
    }
}

// ---------------- CSR aggregation: one wave per dst row, lane = feature (xw in bf16) ----------------
__global__ __launch_bounds__(256) void k_gather(const __hip_bfloat16* __restrict__ xw, const int* __restrict__ colA,
                                                const float* __restrict__ ewA, const int* __restrict__ rowstart,
                                                const float* __restrict__ dinv, float* __restrict__ agg, int N) {
    int wave = (blockIdx.x * 256 + threadIdx.x) >> 6;
    int lane = threadIdx.x & 63;
    if (wave >= N) return;
    int r = wave;
    float di = dinv[r];
    float acc = __bfloat162float(xw[(size_t)r * 64 + lane]) * di * di;  // self-loop
    int b = rowstart[r], e = rowstart[r + 1];
    int i = b;
    for (; i + 3 < e; i += 4) {
        int s0 = colA[i], s1 = colA[i + 1], s2 = colA[i + 2], s3 = colA[i + 3];
        float w0 = ewA[i], w1 = ewA[i + 1], w2 = ewA[i + 2], w3 = ewA[i + 3];
        float x0 = __bfloat162float(xw[(size_t)s0 * 64 + lane]);
        float x1 = __bfloat162float(xw[(size_t)s1 * 64 + lane]);
        float x2 = __bfloat162float(xw[(size_t)s2 * 64 + lane]);
        float x3 = __bfloat162float(xw[(size_t)s3 * 64 + lane]);
        acc += x0 * w0 + x1 * w1 + x2 * w2 + x3 * w3;
    }
    for (; i < e; ++i) acc += __bfloat162float(xw[(size_t)colA[i] * 64 + lane]) * ewA[i];
    agg[(size_t)r * 64 + lane] = acc;
}

// ---------------- BN stats (sum, sumsq per column) ----------------
__global__ __launch_bounds__(256) void k_stats(const float* __restrict__ x, float* __restrict__ stats, int N) {
    int col = threadIdx.x & 63;
    int sub = threadIdx.x >> 6;
    float s = 0.f, s2 = 0.f;
    for (int r = blockIdx.x * 4 + sub; r < N; r += gridDim.x * 4) {
        float v = x[(size_t)r * 64 + col];
        s += v; s2 += v * v;
    }
    __shared__ float sd[2][4][64];
    sd[0][sub][col] = s; sd[1][sub][col] = s2;
    __syncthreads();
    if (sub == 0) {
        s  = sd[0][0][col] + sd[0][1][col] + sd[0][2][col] + sd[0][3][col];
        s2 = sd[1][0][col] + sd[1][1][col] + sd[1][2][col] + sd[1][3][col];
        atomicAdd(&stats[col], s);
        atomicAdd(&stats[64 + col], s2);
    }
}

// ---------------- BN apply + ReLU + residual + weighted emb accumulate ----------------
__global__ __launch_bounds__(256) void k_elem(const float* __restrict__ agg, const float* __restrict__ stats,
                                              const float* __restrict__ gamma, const float* __restrict__ beta,
                                              const float* __restrict__ lw, const float* __restrict__ xprev,
                                              float* __restrict__ xcur, float* __restrict__ emb,
                                              int N, int layer, int L) {
    int i = blockIdx.x * 256 + threadIdx.x;
    if (i >= N * 64) return;
    int c = i & 63;
    float rN = 1.0f / (float)N;
    float mn = stats[c] * rN;
    float var = stats[64 + c] * rN - mn * mn;
    float inv = rsqrtf(var + BN_EPS);
    float v = (agg[i] - mn) * inv * gamma[c] + beta[c];
    v = fmaxf(v, 0.0f);
    if (layer > 0) v += RES_SCALE * xprev[i];
    xcur[i] = v;
    float mx = lw[0];
    for (int j = 1; j < L; ++j) mx = fmaxf(mx, lw[j]);
    float sum = 0.f, wl = 0.f;
    for (int j = 0; j < L; ++j) {
        float e = __expf(lw[j] - mx);
        sum += e;
        if (j == layer) wl = e;
    }
    wl /= sum;
    float prev = (layer == 0) ? 0.0f : emb[i];
    emb[i] = prev + wl * v;
}

extern "C" void kernel_launch(void* const* d_in, const int* in_sizes, int n_in,
                              void* d_out, int out_size, void* d_ws, size_t ws_size,
                              hipStream_t stream) {
    const float* features = (const float*)d_in[0];
    const int*   edges    = (const int*)d_in[1];
    const float* W0       = (const float*)d_in[2];
    // d_in[3] = b0: cancels through BatchNorm (mean subtraction) -> skipped, exact
    const float* Wh       = (const float*)d_in[4];
    // d_in[5] = bh: same
    const float* gamma    = (const float*)d_in[6];
    const float* beta     = (const float*)d_in[7];
    const float* lw       = (const float*)d_in[8];

    const int HID    = in_sizes[3];            // 64
    const int IN_DIM = in_sizes[2] / HID;      // 2000
    const int N      = in_sizes[0] / IN_DIM;   // 50000
    const int E      = in_sizes[1] / 2;        // 1600000
    const int L      = in_sizes[8];            // 4
    float* out = (float*)d_out;

    char* ws = (char*)d_ws;
    auto alloc = [&](size_t bytes) { char* p = ws; ws += (bytes + 255) & ~(size_t)255; return p; };
    int*   counts   = (int*)alloc((size_t)N * 4);
    int*   cursor   = (int*)alloc((size_t)N * 4);
    int*   rowstart = (int*)alloc((size_t)(N + 1) * 4);
    int*   bsum     = (int*)alloc(256 * 4);
    float* dinv     = (float*)alloc((size_t)N * 4);
    float* stats    = (float*)alloc((size_t)L * 128 * 4);
    int*   colA     = (int*)alloc((size_t)E * 4);
    float* ewA      = (float*)alloc((size_t)E * 4);
    short* WT0      = (short*)alloc((size_t)HID * IN_DIM * 2);
    short* WTh      = (short*)alloc((size_t)(L - 1) * HID * HID * 2);
    __hip_bfloat16* xw = (__hip_bfloat16*)alloc((size_t)N * HID * 2);
    float* agg      = (float*)alloc((size_t)N * HID * 4);
    float* x0       = (float*)alloc((size_t)N * HID * 4);
    float* x1       = (float*)alloc((size_t)N * HID * 4);

    int S = L * 128;
    int zgrid = (max(N, S) + 255) / 256;
    k_zero<<<zgrid, 256, 0, stream>>>(counts, cursor, stats, N, S);

    int egrid = (E + 255) / 256;
    int ngrid = (N + 255) / 256;
    k_count<<<egrid, 256, 0, stream>>>(edges, E, counts);
    k_dinv<<<ngrid, 256, 0, stream>>>(counts, dinv, N);

    int B = (N + 1023) / 1024;
    k_scan1<<<B, 256, 0, stream>>>(counts, bsum, N);
    k_scan2<<<1, 64, 0, stream>>>(bsum, B, rowstart, N);
    k_scan3<<<B, 256, 0, stream>>>(counts, bsum, rowstart, N);
    k_scatter<<<egrid, 256, 0, stream>>>(edges, E, rowstart, cursor, dinv, colA, ewA);

    int nk0 = (IN_DIM + 63) / 64;
    k_wt<<<nk0 + (L - 1), 256, 0, stream>>>(W0, Wh, WT0, WTh, IN_DIM);

    int mmgrid = (N + 63) / 64;
    int ggrid  = (N + 3) / 4;
    int elgrid = ((size_t)N * HID + 255) / 256;

    const float* xc_prev = nullptr;
    for (int l = 0; l < L; ++l) {
        const float* Xin = (l == 0) ? features : xc_prev;
        int K = (l == 0) ? IN_DIM : HID;
        const short* WTl = (l == 0) ? WT0 : WTh + (size_t)(l - 1) * HID * HID;
        k_mm<<<mmgrid, 256, 0, stream>>>(Xin, WTl, xw, N, K);
        k_gather<<<ggrid, 256, 0, stream>>>(xw, colA, ewA, rowstart, dinv, agg, N);
        k_stats<<<256, 256, 0, stream>>>(agg, stats + l * 128, N);
        float* xcur = (l % 2 == 0) ? x0 : x1;
        const float* xprev = (l == 0) ? nullptr : ((l % 2 == 0) ? x1 : x0);
        k_elem<<<elgrid, 256, 0, stream>>>(agg, stats + l * 128, gamma + l * HID, beta + l * HID,
                                           lw, xprev, xcur, out, N, l, L);
        xc_prev = xcur;
    }
}